// Round 16
// baseline (154.097 us; speedup 1.0000x reference)
//
#include <hip/hip_runtime.h>
#include <math.h>

// ContextEncoder: B=512, L=10, H=256, D=512.
//  prep: bf16 conversions for Bf/W2/GRU weights only (Af eliminated); resets Cnt.
//  gemm_pq_swz: reads utt fp32 DIRECTLY, in-register bf16 convert after MFMA cluster.
//  stats_kernel: both branches per block + LAST-BLOCK BN1 finalize (reduce_bn1 merged).
//  fused_layer2_half: R12-best config (512x2x2, one branch/block, VGPR 64), bf16 Z2, Part2.
//  postproc: BN2 finalize (anchor-only) + wave-parallel j-dots, fast transcendentals.
//  gemm_gru2 (both GRU GEMMs), gru_final. 7 dispatches.
//  R13 lesson: merging fused branches spills acc to scratch — keep one branch per block.

typedef __attribute__((ext_vector_type(8))) short short8;
typedef __attribute__((ext_vector_type(4))) float f32x4;

__device__ __forceinline__ float softplusf(float x) {
  return x > 0.f ? x + log1pf(expf(-x)) : log1pf(expf(x));
}
__device__ __forceinline__ float wred64(float v) {
#pragma unroll
  for (int o = 32; o > 0; o >>= 1) v += __shfl_down(v, o);
  return v;
}
__device__ __forceinline__ unsigned short f2bf(float f) {
  unsigned int u = __float_as_uint(f);
  u += 0x7fffu + ((u >> 16) & 1u);
  return (unsigned short)(u >> 16);
}
__device__ __forceinline__ float bf2f(unsigned short u) {
  return __uint_as_float(((unsigned int)u) << 16);
}
__device__ __forceinline__ float tanh_fast(float x) {
  float ex = __expf(2.f * x);
  return 1.f - 2.f / (ex + 1.f);
}
__device__ __forceinline__ float sigmoid_fast(float x) {
  return 1.f / (1.f + __expf(-x));
}
__device__ __forceinline__ short8 pack8(const float* __restrict__ p) {
  float4 v0 = *(const float4*)p;
  float4 v1 = *(const float4*)(p + 4);
  short8 r;
  r[0] = (short)f2bf(v0.x); r[1] = (short)f2bf(v0.y);
  r[2] = (short)f2bf(v0.z); r[3] = (short)f2bf(v0.w);
  r[4] = (short)f2bf(v1.x); r[5] = (short)f2bf(v1.y);
  r[6] = (short)f2bf(v1.z); r[7] = (short)f2bf(v1.w);
  return r;
}
__device__ __forceinline__ short8 cvt8(float4 v0, float4 v1) {
  short8 r;
  r[0] = (short)f2bf(v0.x); r[1] = (short)f2bf(v0.y);
  r[2] = (short)f2bf(v0.z); r[3] = (short)f2bf(v0.w);
  r[4] = (short)f2bf(v1.x); r[5] = (short)f2bf(v1.y);
  r[6] = (short)f2bf(v1.z); r[7] = (short)f2bf(v1.w);
  return r;
}

// ---------------- prep: bf16 conversions (Bf/W2/GRU only) + Cnt reset ----------------
// Items (short8): Bf 65536, W2fa 8192, W2fs 8192, wi 49152, wh 24576 -> 155648 = 608x256.
__global__ __launch_bounds__(256) void prep_weights(
    const float* __restrict__ a_w1, const float* __restrict__ s_w1,
    const float* __restrict__ a_w2, const float* __restrict__ s_w2,
    const float* __restrict__ gru_wi, const float* __restrict__ gru_wh,
    unsigned short* __restrict__ Bf,
    unsigned short* __restrict__ W2fa, unsigned short* __restrict__ W2fs,
    unsigned short* __restrict__ wibf, unsigned short* __restrict__ whbf,
    unsigned int* __restrict__ Cnt) {
  if (blockIdx.x == 0 && threadIdx.x == 0) *Cnt = 0;
  int i = blockIdx.x * 256 + threadIdx.x;
  if (i < 65536) {  // Bf: i = cb*4096 + ks*256 + cf*64 + lane
    int lane = i & 63, cf = (i >> 6) & 3, ks = (i >> 8) & 15, cb = i >> 12;
    int c = cb * 64 + cf * 16 + (lane & 15);
    int k = ks * 32 + (lane >> 4) * 8;
    const float* src;
    if (c < 256)       src = &a_w1[c * 1024 + k];
    else if (c < 512)  src = &a_w1[(c - 256) * 1024 + 512 + k];
    else if (c < 768)  src = &s_w1[(c - 512) * 1024 + k];
    else               src = &s_w1[(c - 768) * 1024 + 512 + k];
    *(short8*)&Bf[i * 8] = pack8(src);
    return;
  }
  i -= 65536;
  if (i < 8192) {  // W2fa: i = cb*2048 + ks*256 + cf*64 + lane
    int lane = i & 63, cf = (i >> 6) & 3, ks = (i >> 8) & 7, cb = i >> 11;
    int c = cb * 64 + cf * 16 + (lane & 15);
    int k = ks * 32 + (lane >> 4) * 8;
    *(short8*)&W2fa[i * 8] = pack8(&a_w2[c * 256 + k]);
    return;
  }
  i -= 8192;
  if (i < 8192) {  // W2fs
    int lane = i & 63, cf = (i >> 6) & 3, ks = (i >> 8) & 7, cb = i >> 11;
    int c = cb * 64 + cf * 16 + (lane & 15);
    int k = ks * 32 + (lane >> 4) * 8;
    *(short8*)&W2fs[i * 8] = pack8(&s_w2[c * 256 + k]);
    return;
  }
  i -= 8192;
  if (i < 49152) { *(short8*)&wibf[i * 8] = pack8(&gru_wi[i * 8]); return; }
  i -= 49152;
  if (i < 24576) *(short8*)&whbf[i * 8] = pack8(&gru_wh[i * 8]);
}

// ---------------- PQ GEMM: utt fp32 direct, in-register bf16 convert; 64x256 tile ----------------
__global__ __launch_bounds__(256) void gemm_pq_swz(
    const float* __restrict__ utt, const unsigned short* __restrict__ Bf,
    unsigned short* __restrict__ C) {
  int t = threadIdx.x;
  int w = t >> 6, l = t & 63, li = l & 15, lg = l >> 4;
  int rb0 = blockIdx.x * 4;
  int cb = blockIdx.y * 4 + w;
  const unsigned short* Bb = Bf + cb * (16 * 4 * 512);
  f32x4 acc[4][4] = {};
  short8 acur[4], bcur[4], bnxt[4];
  float4 araw0[4], araw1[4];
  const float* Arow[4];
#pragma unroll
  for (int fr = 0; fr < 4; ++fr) Arow[fr] = utt + ((rb0 + fr) * 16 + li) * 512 + lg * 8;
#pragma unroll
  for (int fr = 0; fr < 4; ++fr) {
    araw0[fr] = *(const float4*)&Arow[fr][0];
    araw1[fr] = *(const float4*)&Arow[fr][4];
  }
#pragma unroll
  for (int cf = 0; cf < 4; ++cf) bcur[cf] = *(const short8*)&Bb[(0 * 4 + cf) * 512 + l * 8];
#pragma unroll
  for (int fr = 0; fr < 4; ++fr) acur[fr] = cvt8(araw0[fr], araw1[fr]);
  for (int ks = 0; ks < 16; ++ks) {
    if (ks < 15) {
#pragma unroll
      for (int fr = 0; fr < 4; ++fr) {
        araw0[fr] = *(const float4*)&Arow[fr][(ks + 1) * 32];
        araw1[fr] = *(const float4*)&Arow[fr][(ks + 1) * 32 + 4];
      }
#pragma unroll
      for (int cf = 0; cf < 4; ++cf) bnxt[cf] = *(const short8*)&Bb[((ks + 1) * 4 + cf) * 512 + l * 8];
    }
#pragma unroll
    for (int fr = 0; fr < 4; ++fr)
#pragma unroll
      for (int cf = 0; cf < 4; ++cf)
        acc[fr][cf] = __builtin_amdgcn_mfma_f32_16x16x32_bf16(acur[fr], bcur[cf], acc[fr][cf], 0, 0, 0);
    if (ks < 15) {
#pragma unroll
      for (int fr = 0; fr < 4; ++fr) acur[fr] = cvt8(araw0[fr], araw1[fr]);
#pragma unroll
      for (int cf = 0; cf < 4; ++cf) bcur[cf] = bnxt[cf];
    }
  }
  int rowBase = blockIdx.x * 64, colBase = cb * 64;
#pragma unroll
  for (int fr = 0; fr < 4; ++fr)
#pragma unroll
    for (int reg = 0; reg < 4; ++reg) {
      int r = rowBase + fr * 16 + lg * 4 + reg;
      unsigned short* crow = C + r * 1024 + colBase + li;
#pragma unroll
      for (int cf = 0; cf < 4; ++cf) crow[cf * 16] = f2bf(acc[fr][cf][reg]);
    }
}

// ---------------- BN1 stats: both branches per block + last-block finalize ----------------
__global__ __launch_bounds__(256) void stats_kernel(
    const unsigned short* __restrict__ PQ, const float* __restrict__ a_b1,
    const float* __restrict__ s_b1,
    const float* __restrict__ a_g1, const float* __restrict__ a_be1,
    const float* __restrict__ s_g1, const float* __restrict__ s_be1,
    float* __restrict__ Part, float* __restrict__ ST, unsigned int* __restrict__ Cnt) {
  __shared__ float lbins[4][32];
  int b = blockIdx.x, t = threadIdx.x;
  int w = t >> 6, l = t & 63;
  int half = t >> 7;        // 0 = branch a, 1 = branch s
  int tt = t & 127;
  int c0 = tt * 2;
  int p_off = half ? 512 : 0;
  const unsigned short* base = PQ + b * 10240 + p_off;
  const float* b1h = half ? s_b1 : a_b1;
  float Q0[10], Q1[10];
#pragma unroll
  for (int j = 0; j < 10; ++j) {
    unsigned int qq = *(const unsigned int*)&base[j * 1024 + 256 + c0];
    Q0[j] = bf2f((unsigned short)qq);
    Q1[j] = bf2f((unsigned short)(qq >> 16));
  }
  float sq = 0.f, sq2 = 0.f, qb0 = 0.f, qb1 = 0.f;
#pragma unroll
  for (int j = 0; j < 10; ++j) {
    sq += Q0[j] + Q1[j];
    sq2 += Q0[j] * Q0[j] + Q1[j] * Q1[j];
    qb0 += Q0[j];
    qb1 += Q1[j];
  }
  qb0 *= 0.1f;
  qb1 *= 0.1f;
  float b10 = b1h[c0], b11 = b1h[c0 + 1];
  float r;
  r = wred64(sq);  if (l == 0) lbins[w][0] = r;
  r = wred64(sq2); if (l == 0) lbins[w][1] = r;
#pragma unroll
  for (int i = 0; i < 10; ++i) {
    unsigned int pp = *(const unsigned int*)&base[i * 1024 + c0];
    float P0 = bf2f((unsigned short)pp);
    float P1 = bf2f((unsigned short)(pp >> 16));
    float a0 = P0 + b10, a1 = P1 + b11;
    r = wred64(P0 + P1);                 if (l == 0) lbins[w][2 + i * 3] = r;
    r = wred64(a0 * a0 + a1 * a1);       if (l == 0) lbins[w][3 + i * 3] = r;
    r = wred64(a0 * qb0 + a1 * qb1);     if (l == 0) lbins[w][4 + i * 3] = r;
  }
  __syncthreads();
  if (t < 64) {
    int br = t >> 5, s = t & 31;
    Part[(b * 2 + br) * 32 + s] = lbins[br * 2][s] + lbins[br * 2 + 1][s];
  }
  // ---- last-block BN1 finalize ----
  __threadfence();
  __syncthreads();
  __shared__ int isLast;
  if (t == 0) isLast = (atomicAdd(Cnt, 1u) == 511u) ? 1 : 0;
  __syncthreads();
  if (!isLast) return;
  __threadfence();
  __shared__ float tmp[256];
  __shared__ float mom[32];
  for (int br = 0; br < 2; ++br) {
    int v = t & 31, c = t >> 5;
    float s = 0.f;
    for (int bb = c * 64; bb < c * 64 + 64; ++bb) s += Part[(bb * 2 + br) * 32 + v];
    tmp[t] = s;
    __syncthreads();
    if (t < 32) {
      float m = 0.f;
#pragma unroll
      for (int k = 0; k < 8; ++k) m += tmp[k * 32 + t];
      mom[t] = m;
    }
    __syncthreads();
    if (t < 10) {
      int i = t;
      const float* b1 = br ? s_b1 : a_b1;
      float bsum = 0.f;
      for (int h = 0; h < 256; ++h) bsum += b1[h];
      float meanb1 = bsum * (1.f / 256.f);
      const float invBH = 1.f / (512.f * 256.f);
      const float invBLH = 1.f / (512.f * 10.f * 256.f);
      float SP = mom[2 + i * 3], SA2 = mom[3 + i * 3], SPQ = mom[4 + i * 3];
      float SQ = mom[0], SQ2 = mom[1];
      float mean = SP * invBH + meanb1 + SQ * invBLH;
      float Ez2 = SA2 * invBH + 2.f * SPQ * invBH + SQ2 * invBLH;
      float var = Ez2 - mean * mean;
      float g = br ? s_g1[i] : a_g1[i];
      float be = br ? s_be1[i] : a_be1[i];
      float sc = g / sqrtf(var + 1e-5f);
      ST[64 + br * 20 + i] = sc;
      ST[64 + br * 20 + 10 + i] = be - mean * sc;
    }
    __syncthreads();
  }
}

// ---------------- fused layer2 (R12-best): block = (dialog, i-half, branch) ----------------
// Part2 layout: sum at [(br*10+i)*512 + b], sumsq at [10240 + (br*10+i)*512 + b].
__global__ __launch_bounds__(256, 4) void fused_layer2_half(
    const unsigned short* __restrict__ PQ, const float* __restrict__ ST,
    const float* __restrict__ a_b1, const float* __restrict__ s_b1,
    const unsigned short* __restrict__ W2fa, const unsigned short* __restrict__ W2fs,
    const float* __restrict__ a_b2, const float* __restrict__ s_b2,
    const int* __restrict__ cl, unsigned short* __restrict__ Z2a, unsigned short* __restrict__ Z2s,
    float* __restrict__ Part2) {
  __shared__ __align__(16) unsigned short Atile[64][264];
  __shared__ float bins[10];
  int b = blockIdx.x, half = blockIdx.y, br = blockIdx.z;
  int i0 = half * 5;
  int p_off = br ? 512 : 0;
  const float* b1 = br ? s_b1 : a_b1;
  const unsigned short* W2f = br ? W2fs : W2fa;
  const float* b2 = br ? s_b2 : a_b2;
  unsigned short* Z2out = br ? Z2s : Z2a;
  int sc_off = br ? 84 : 64;
  int t = threadIdx.x;
  int anc = cl[b] - 1;
  if (t < 10) bins[t] = 0.f;
  // ---- early W2/bias prefetch ----
  int w = t >> 6, l = t & 63, li = l & 15, lg = l >> 4;
  int colBase = w * 64;
  const unsigned short* Wb = W2f + w * (8 * 4 * 512);
  short8 bcur[4], bnxt[4];
#pragma unroll
  for (int cf = 0; cf < 4; ++cf) bcur[cf] = *(const short8*)&Wb[(0 * 4 + cf) * 512 + l * 8];
  float b2v[4];
#pragma unroll
  for (int cf = 0; cf < 4; ++cf) b2v[cf] = b2[colBase + cf * 16 + li];
  for (int idx = t; idx < 14 * 264; idx += 256) (&Atile[50][0])[idx] = 0;
  // ---- h1 phase: thread t = column c; bf16 P/Q loads ----
  {
    int c = t;
    float b1c = b1[c];
    float P[5], Q[10];
#pragma unroll
    for (int j = 0; j < 10; ++j) Q[j] = bf2f(PQ[(b * 10 + j) * 1024 + p_off + 256 + c]);
#pragma unroll
    for (int il = 0; il < 5; ++il) P[il] = bf2f(PQ[(b * 10 + i0 + il) * 1024 + p_off + c]);
#pragma unroll
    for (int il = 0; il < 5; ++il) {
      float sc = ST[sc_off + i0 + il], sh = ST[sc_off + 10 + i0 + il];
      float base = (P[il] + b1c) * sc + sh;
#pragma unroll
      for (int j = 0; j < 10; ++j) {
        float z = base + Q[j] * sc;
        float h;
        if (br) {
          float ex = __expf(2.f * z);
          h = 1.f - 2.f / (ex + 1.f);
        } else {
          h = fmaxf(z, 0.f);
        }
        Atile[il * 10 + j][c] = f2bf(h);
      }
    }
  }
  __syncthreads();
  // ---- MFMA: wave w owns 64 cols, 64 rows (50 valid); W2 frags coalesced + prefetched ----
  f32x4 acc[4][4] = {};
  for (int ks = 0; ks < 8; ++ks) {
    if (ks < 7) {
#pragma unroll
      for (int cf = 0; cf < 4; ++cf) bnxt[cf] = *(const short8*)&Wb[((ks + 1) * 4 + cf) * 512 + l * 8];
    }
    int ka = ks * 32 + lg * 8;
#pragma unroll
    for (int fr = 0; fr < 4; ++fr) {
      short8 afr = *(const short8*)&Atile[fr * 16 + li][ka];
#pragma unroll
      for (int cf = 0; cf < 4; ++cf)
        acc[fr][cf] = __builtin_amdgcn_mfma_f32_16x16x32_bf16(afr, bcur[cf], acc[fr][cf], 0, 0, 0);
    }
#pragma unroll
    for (int cf = 0; cf < 4; ++cf) bcur[cf] = bnxt[cf];
  }
  // ---- epilogue: bias, anchor-row writes (bf16), BN2 bins (LDS only) ----
#pragma unroll
  for (int fr = 0; fr < 4; ++fr) {
#pragma unroll
    for (int reg = 0; reg < 4; ++reg) {
      int row = fr * 16 + lg * 4 + reg;
      bool valid = row < 50;
      int il = row / 10, jj = row - il * 10;
      float z0 = acc[fr][0][reg] + b2v[0];
      float z1 = acc[fr][1][reg] + b2v[1];
      float z2 = acc[fr][2][reg] + b2v[2];
      float z3 = acc[fr][3][reg] + b2v[3];
      if (valid && (i0 + il) == anc) {
        unsigned short* dst = Z2out + (b * 10 + jj) * 256 + colBase + li;
        dst[0] = f2bf(z0); dst[16] = f2bf(z1); dst[32] = f2bf(z2); dst[48] = f2bf(z3);
      }
      float s = valid ? (z0 + z1 + z2 + z3) : 0.f;
      float q = valid ? (z0 * z0 + z1 * z1 + z2 * z2 + z3 * z3) : 0.f;
#pragma unroll
      for (int o = 1; o < 16; o <<= 1) {
        s += __shfl_xor(s, o);
        q += __shfl_xor(q, o);
      }
      if (li == 0 && valid) {
        atomicAdd(&bins[il], s);
        atomicAdd(&bins[5 + il], q);
      }
    }
  }
  __syncthreads();
  if (t < 5) {
    Part2[(br * 10 + i0 + t) * 512 + b] = bins[t];
    Part2[10240 + (br * 10 + i0 + t) * 512 + b] = bins[5 + t];
  }
}

// ---------------- merged GRU GEMMs: grid (16, 3, 2), N=768 ----------------
__global__ __launch_bounds__(256) void gemm_gru2(
    const unsigned short* __restrict__ A0, const unsigned short* __restrict__ B0,
    float* __restrict__ C0, const float* __restrict__ bias0,
    const unsigned short* __restrict__ A1, const unsigned short* __restrict__ B1,
    float* __restrict__ C1, const float* __restrict__ bias1) {
  const unsigned short* A; const unsigned short* Bw; float* C; const float* bias; int K;
  if (blockIdx.z == 0) { A = A0; Bw = B0; C = C0; bias = bias0; K = 512; }
  else                 { A = A1; Bw = B1; C = C1; bias = bias1; K = 256; }
  int t = threadIdx.x;
  int w = t >> 6, l = t & 63, li = l & 15, lg = l >> 4;
  int rowBase = blockIdx.x * 32;
  int colBase = blockIdx.y * 256 + w * 64;
  f32x4 acc[2][4] = {};
  const unsigned short* Arow[2];
  const unsigned short* Brow[4];
#pragma unroll
  for (int fr = 0; fr < 2; ++fr) Arow[fr] = A + (rowBase + fr * 16 + li) * K;
#pragma unroll
  for (int cf = 0; cf < 4; ++cf) Brow[cf] = Bw + (colBase + cf * 16 + li) * K;
  for (int ks = 0; ks < K / 32; ++ks) {
    int ka = ks * 32 + lg * 8;
    short8 afr[2], bfr[4];
#pragma unroll
    for (int fr = 0; fr < 2; ++fr) afr[fr] = *(const short8*)&Arow[fr][ka];
#pragma unroll
    for (int cf = 0; cf < 4; ++cf) bfr[cf] = *(const short8*)&Brow[cf][ka];
#pragma unroll
    for (int fr = 0; fr < 2; ++fr)
#pragma unroll
      for (int cf = 0; cf < 4; ++cf)
        acc[fr][cf] = __builtin_amdgcn_mfma_f32_16x16x32_bf16(afr[fr], bfr[cf], acc[fr][cf], 0, 0, 0);
  }
  float b2v[4];
#pragma unroll
  for (int cf = 0; cf < 4; ++cf) b2v[cf] = bias[colBase + cf * 16 + li];
#pragma unroll
  for (int fr = 0; fr < 2; ++fr)
#pragma unroll
    for (int reg = 0; reg < 4; ++reg) {
      int r = rowBase + fr * 16 + lg * 4 + reg;
      float* crow = C + r * 768 + colBase + li;
#pragma unroll
      for (int cf = 0; cf < 4; ++cf) crow[cf * 16] = acc[fr][cf][reg] + b2v[cf];
    }
}

// ---------------- postproc: BN2 finalize (anchor-only) + wave-parallel j-dots ----------------
__global__ __launch_bounds__(256) void postproc_kernel(
    const float* __restrict__ Part2,
    const float* __restrict__ a_g2, const float* __restrict__ a_be2,
    const float* __restrict__ s_g2, const float* __restrict__ s_be2,
    const unsigned short* __restrict__ Z2a, const unsigned short* __restrict__ Z2s,
    const float* __restrict__ a_w3, const float* __restrict__ a_b3,
    const float* __restrict__ mu_w, const float* __restrict__ mu_b,
    const float* __restrict__ sg_w, const float* __restrict__ sg_b,
    const float* __restrict__ aij_eps, const float* __restrict__ sij_eps,
    const int* __restrict__ cl, const float* __restrict__ utt,
    unsigned short* __restrict__ msgbf, unsigned short* __restrict__ h0bf,
    float* __restrict__ h0out) {
  int b = blockIdx.x, t = threadIdx.x;
  int w = t >> 6, l = t & 63;
  int a = cl[b] - 1;
  __shared__ float bn2r[4];
  {
    int p = (w >> 1) * 10 + a;
    int off = (w & 1) ? 10240 : 0;
    float s = 0.f;
#pragma unroll
    for (int k = 0; k < 8; ++k) s += Part2[off + p * 512 + l + k * 64];
    s = wred64(s);
    if (l == 0) bn2r[w] = s;
  }
  __syncthreads();
  __shared__ float sc2[4];  // sc2a, sh2a, sc2s, sh2s
  if (t < 2) {
    int br = t;
    const float invN = 1.f / (512.f * 10.f * 256.f);
    float m = bn2r[br * 2 + 0] * invN;
    float v = bn2r[br * 2 + 1] * invN - m * m;
    float g = br ? s_g2[a] : a_g2[a];
    float be = br ? s_be2[a] : a_be2[a];
    float sc = g / sqrtf(v + 1e-5f);
    sc2[br * 2] = sc;
    sc2[br * 2 + 1] = be - m * sc;
  }
  __syncthreads();
  float sc2a = sc2[0], sh2a = sc2[1], sc2s = sc2[2], sh2s = sc2[3];
  __shared__ float red[30];
#pragma unroll
  for (int m = 0; m < 3; ++m) {
    int j = w + 4 * m;
    if (j < 10) {
      float pa = 0.f, pm = 0.f, ps = 0.f;
#pragma unroll
      for (int cc = 0; cc < 4; ++cc) {
        int c = l + cc * 64;
        float za = bf2f(Z2a[(b * 10 + j) * 256 + c]);
        float va = fmaxf(za * sc2a + sh2a, 0.f);
        float zs = bf2f(Z2s[(b * 10 + j) * 256 + c]);
        float vs = tanh_fast(zs * sc2s + sh2s);
        pa += va * a_w3[c];
        pm += vs * mu_w[c];
        ps += vs * sg_w[c];
      }
      pa = wred64(pa); pm = wred64(pm); ps = wred64(ps);
      if (l == 0) { red[j] = pa; red[10 + j] = pm; red[20 + j] = ps; }
    }
  }
  __syncthreads();
  __shared__ float pw[10];
  __shared__ float wijs[16];
  if (t < 10) {
    int j = t;
    float amij = red[j] + a_b3[0];
    float amu = softplusf(amij) + 0.01f;
    float astd = sqrtf(softplusf((1.f - amu) * amu) + 0.01f);
    float ae = aij_eps[b * 100 + a * 10 + j];
    float aij = softplusf(ae * astd + amu) + 0.01f;
    float smu = red[10 + j] + mu_b[0];
    float ssg = red[20 + j] + sg_b[0];
    float se = sij_eps[b * 100 + a * 10 + j];
    float sij = se * sqrtf(aij * ssg * ssg) + aij * smu;
    wijs[j] = aij * sij;
  }
  __syncthreads();
  if (t == 0) {
    float mx = -1e30f;
    for (int j = 0; j < a; ++j) mx = fmaxf(mx, wijs[j]);
    float e[10];
    float den = 0.f;
    for (int j = 0; j < a; ++j) { e[j] = __expf(wijs[j] - mx); den += e[j]; }
    for (int j = 0; j < 10; ++j) pw[j] = (j < a) ? e[j] / den : 0.f;
  }
  __syncthreads();
#pragma unroll
  for (int dd = 0; dd < 2; ++dd) {
    int d = t + dd * 256;
    float mv = 0.f;
#pragma unroll
    for (int j = 0; j < 10; ++j) mv += pw[j] * utt[(b * 10 + j) * 512 + d];
    msgbf[b * 512 + d] = f2bf(mv);
  }
  float u1 = utt[(b * 10 + a) * 512 + t];
  float u2 = utt[(b * 10 + a) * 512 + 256 + t];
  float h0v = u1 + u2;
  h0out[b * 256 + t] = h0v;
  h0bf[b * 256 + t] = f2bf(h0v);
}

// ---------------- GRU elementwise (fast transcendentals) ----------------
__global__ __launch_bounds__(256) void gru_final(const float* __restrict__ gi,
                                                 const float* __restrict__ gh,
                                                 const float* __restrict__ h0,
                                                 float* __restrict__ out) {
  int idx = blockIdx.x * 256 + threadIdx.x;
  int b = idx >> 8, h = idx & 255;
  float ir = gi[b * 768 + h], iz = gi[b * 768 + 256 + h], inn = gi[b * 768 + 512 + h];
  float hr = gh[b * 768 + h], hz = gh[b * 768 + 256 + h], hn = gh[b * 768 + 512 + h];
  float r = sigmoid_fast(ir + hr);
  float z = sigmoid_fast(iz + hz);
  float n = tanh_fast(inn + r * hn);
  out[idx] = (1.f - z) * n + z * h0[b * 256 + h];
}

extern "C" void kernel_launch(void* const* d_in, const int* in_sizes, int n_in,
                              void* d_out, int out_size, void* d_ws, size_t ws_size,
                              hipStream_t stream) {
  const float* utt = (const float*)d_in[0];
  const float* aij_eps = (const float*)d_in[1];
  const float* sij_eps = (const float*)d_in[2];
  const int* cl = (const int*)d_in[3];
  const float* a_w1 = (const float*)d_in[4];
  const float* a_b1 = (const float*)d_in[5];
  const float* a_g1 = (const float*)d_in[6];
  const float* a_be1 = (const float*)d_in[7];
  const float* a_w2 = (const float*)d_in[8];
  const float* a_b2 = (const float*)d_in[9];
  const float* a_g2 = (const float*)d_in[10];
  const float* a_be2 = (const float*)d_in[11];
  const float* a_w3 = (const float*)d_in[12];
  const float* a_b3 = (const float*)d_in[13];
  const float* s_w1 = (const float*)d_in[14];
  const float* s_b1 = (const float*)d_in[15];
  const float* s_g1 = (const float*)d_in[16];
  const float* s_be1 = (const float*)d_in[17];
  const float* s_w2 = (const float*)d_in[18];
  const float* s_b2 = (const float*)d_in[19];
  const float* s_g2 = (const float*)d_in[20];
  const float* s_be2 = (const float*)d_in[21];
  const float* mu_w = (const float*)d_in[22];
  const float* mu_b = (const float*)d_in[23];
  const float* sg_w = (const float*)d_in[24];
  const float* sg_b = (const float*)d_in[25];
  const float* gru_wi = (const float*)d_in[26];
  const float* gru_wh = (const float*)d_in[27];
  const float* gru_bi = (const float*)d_in[28];
  const float* gru_bh = (const float*)d_in[29];

  float* ws = (float*)d_ws;
  float* ST = ws;                                            // 256 floats
  unsigned short* Af_unused = (unsigned short*)(ws + 256);   // (hole, kept for layout)
  unsigned short* Bf = Af_unused + 2621440;                  // 524288 sh
  unsigned short* W2fa = Bf + 524288;                        // 65536 sh
  unsigned short* W2fs = W2fa + 65536;                       // 65536 sh
  unsigned short* wibf = W2fs + 65536;                       // 393216 sh
  unsigned short* whbf = wibf + 393216;                      // 196608 sh
  float* PQf = (float*)(whbf + 196608);                      // region: 5242880 f (PQ bf16 uses half)
  unsigned short* PQ = (unsigned short*)PQf;                 // 5242880 sh used
  unsigned short* Z2a = (unsigned short*)(PQf + 5242880);    // 1310720 sh
  unsigned short* Z2s = Z2a + 1310720;                       // 1310720 sh
  float* Part = PQf + 5242880 + 1310720;                     // 32768 f
  float* Part2 = Part + 32768;                               // 20480 f
  unsigned int* Cnt = (unsigned int*)(Part2 + 20480);        // 1 u32
  // postproc/GRU buffers alias the tail of the PQ region (PQ bf16 occupies first half only)
  float* tailf = PQf + 2621440;                              // 2621440 f free
  unsigned short* msgbf = (unsigned short*)tailf;            // 262144 sh
  unsigned short* h0bf = msgbf + 262144;                     // 131072 sh
  float* h0 = tailf + 196608;                                // 131072 f
  float* gi = tailf + 327680;                                // 393216 f
  float* gh = gi + 393216;                                   // 393216 f

  prep_weights<<<608, 256, 0, stream>>>(a_w1, s_w1, a_w2, s_w2, gru_wi, gru_wh,
                                        Bf, W2fa, W2fs, wibf, whbf, Cnt);
  gemm_pq_swz<<<dim3(80, 4), 256, 0, stream>>>(utt, Bf, PQ);
  stats_kernel<<<512, 256, 0, stream>>>(PQ, a_b1, s_b1, a_g1, a_be1, s_g1, s_be1,
                                        Part, ST, Cnt);
  fused_layer2_half<<<dim3(512, 2, 2), 256, 0, stream>>>(PQ, ST, a_b1, s_b1, W2fa, W2fs,
                                                         a_b2, s_b2, cl, Z2a, Z2s, Part2);
  postproc_kernel<<<512, 256, 0, stream>>>(Part2, a_g2, a_be2, s_g2, s_be2,
                                           Z2a, Z2s, a_w3, a_b3, mu_w, mu_b, sg_w, sg_b,
                                           aij_eps, sij_eps, cl, utt, msgbf, h0bf, h0);
  gemm_gru2<<<dim3(16, 3, 2), 256, 0, stream>>>(msgbf, wibf, gi, gru_bi,
                                                h0bf, whbf, gh, gru_bh);
  gru_final<<<512, 256, 0, stream>>>(gi, gh, h0, (float*)d_out);
}

// Round 17
// 134.956 us; speedup vs baseline: 1.1418x; 1.1418x over previous
//
#include <hip/hip_runtime.h>
#include <math.h>

// ContextEncoder: B=512, L=10, H=256, D=512.
//  prep: bf16 conversions for Bf/W2/GRU weights only (Af eliminated).
//  gemm_pq_swz: reads utt fp32 DIRECTLY, in-register bf16 convert (no Af staging).
//  stats_kernel: both branches per block -> Part; reduce_bn1 (2 blocks) finalizes BN1.
//  fused_layer2_half: R12-best config (512x2x2, one branch/block, VGPR 64), bf16 Z2, Part2.
//  postproc: BN2 finalize (anchor-only) + wave-parallel j-dots, fast transcendentals.
//  gemm_gru2 (both GRU GEMMs), gru_final. 8 dispatches.
//  R13 lesson: merging fused branches spills acc to scratch.
//  R16 lesson: per-block __threadfence (last-block pattern) costs ~50 us on 8-XCD MI355X —
//  a tiny extra dispatch is far cheaper than device-scope fences.

typedef __attribute__((ext_vector_type(8))) short short8;
typedef __attribute__((ext_vector_type(4))) float f32x4;

__device__ __forceinline__ float softplusf(float x) {
  return x > 0.f ? x + log1pf(expf(-x)) : log1pf(expf(x));
}
__device__ __forceinline__ float wred64(float v) {
#pragma unroll
  for (int o = 32; o > 0; o >>= 1) v += __shfl_down(v, o);
  return v;
}
__device__ __forceinline__ unsigned short f2bf(float f) {
  unsigned int u = __float_as_uint(f);
  u += 0x7fffu + ((u >> 16) & 1u);
  return (unsigned short)(u >> 16);
}
__device__ __forceinline__ float bf2f(unsigned short u) {
  return __uint_as_float(((unsigned int)u) << 16);
}
__device__ __forceinline__ float tanh_fast(float x) {
  float ex = __expf(2.f * x);
  return 1.f - 2.f / (ex + 1.f);
}
__device__ __forceinline__ float sigmoid_fast(float x) {
  return 1.f / (1.f + __expf(-x));
}
__device__ __forceinline__ short8 pack8(const float* __restrict__ p) {
  float4 v0 = *(const float4*)p;
  float4 v1 = *(const float4*)(p + 4);
  short8 r;
  r[0] = (short)f2bf(v0.x); r[1] = (short)f2bf(v0.y);
  r[2] = (short)f2bf(v0.z); r[3] = (short)f2bf(v0.w);
  r[4] = (short)f2bf(v1.x); r[5] = (short)f2bf(v1.y);
  r[6] = (short)f2bf(v1.z); r[7] = (short)f2bf(v1.w);
  return r;
}
__device__ __forceinline__ short8 cvt8(float4 v0, float4 v1) {
  short8 r;
  r[0] = (short)f2bf(v0.x); r[1] = (short)f2bf(v0.y);
  r[2] = (short)f2bf(v0.z); r[3] = (short)f2bf(v0.w);
  r[4] = (short)f2bf(v1.x); r[5] = (short)f2bf(v1.y);
  r[6] = (short)f2bf(v1.z); r[7] = (short)f2bf(v1.w);
  return r;
}

// ---------------- prep: bf16 conversions (Bf/W2/GRU only) ----------------
// Items (short8): Bf 65536, W2fa 8192, W2fs 8192, wi 49152, wh 24576 -> 155648 = 608x256.
__global__ __launch_bounds__(256) void prep_weights(
    const float* __restrict__ a_w1, const float* __restrict__ s_w1,
    const float* __restrict__ a_w2, const float* __restrict__ s_w2,
    const float* __restrict__ gru_wi, const float* __restrict__ gru_wh,
    unsigned short* __restrict__ Bf,
    unsigned short* __restrict__ W2fa, unsigned short* __restrict__ W2fs,
    unsigned short* __restrict__ wibf, unsigned short* __restrict__ whbf) {
  int i = blockIdx.x * 256 + threadIdx.x;
  if (i < 65536) {  // Bf: i = cb*4096 + ks*256 + cf*64 + lane
    int lane = i & 63, cf = (i >> 6) & 3, ks = (i >> 8) & 15, cb = i >> 12;
    int c = cb * 64 + cf * 16 + (lane & 15);
    int k = ks * 32 + (lane >> 4) * 8;
    const float* src;
    if (c < 256)       src = &a_w1[c * 1024 + k];
    else if (c < 512)  src = &a_w1[(c - 256) * 1024 + 512 + k];
    else if (c < 768)  src = &s_w1[(c - 512) * 1024 + k];
    else               src = &s_w1[(c - 768) * 1024 + 512 + k];
    *(short8*)&Bf[i * 8] = pack8(src);
    return;
  }
  i -= 65536;
  if (i < 8192) {  // W2fa: i = cb*2048 + ks*256 + cf*64 + lane
    int lane = i & 63, cf = (i >> 6) & 3, ks = (i >> 8) & 7, cb = i >> 11;
    int c = cb * 64 + cf * 16 + (lane & 15);
    int k = ks * 32 + (lane >> 4) * 8;
    *(short8*)&W2fa[i * 8] = pack8(&a_w2[c * 256 + k]);
    return;
  }
  i -= 8192;
  if (i < 8192) {  // W2fs
    int lane = i & 63, cf = (i >> 6) & 3, ks = (i >> 8) & 7, cb = i >> 11;
    int c = cb * 64 + cf * 16 + (lane & 15);
    int k = ks * 32 + (lane >> 4) * 8;
    *(short8*)&W2fs[i * 8] = pack8(&s_w2[c * 256 + k]);
    return;
  }
  i -= 8192;
  if (i < 49152) { *(short8*)&wibf[i * 8] = pack8(&gru_wi[i * 8]); return; }
  i -= 49152;
  if (i < 24576) *(short8*)&whbf[i * 8] = pack8(&gru_wh[i * 8]);
}

// ---------------- PQ GEMM: utt fp32 direct, in-register bf16 convert; 64x256 tile ----------------
__global__ __launch_bounds__(256) void gemm_pq_swz(
    const float* __restrict__ utt, const unsigned short* __restrict__ Bf,
    unsigned short* __restrict__ C) {
  int t = threadIdx.x;
  int w = t >> 6, l = t & 63, li = l & 15, lg = l >> 4;
  int rb0 = blockIdx.x * 4;
  int cb = blockIdx.y * 4 + w;
  const unsigned short* Bb = Bf + cb * (16 * 4 * 512);
  f32x4 acc[4][4] = {};
  short8 acur[4], bcur[4], bnxt[4];
  float4 araw0[4], araw1[4];
  const float* Arow[4];
#pragma unroll
  for (int fr = 0; fr < 4; ++fr) Arow[fr] = utt + ((rb0 + fr) * 16 + li) * 512 + lg * 8;
#pragma unroll
  for (int fr = 0; fr < 4; ++fr) {
    araw0[fr] = *(const float4*)&Arow[fr][0];
    araw1[fr] = *(const float4*)&Arow[fr][4];
  }
#pragma unroll
  for (int cf = 0; cf < 4; ++cf) bcur[cf] = *(const short8*)&Bb[(0 * 4 + cf) * 512 + l * 8];
#pragma unroll
  for (int fr = 0; fr < 4; ++fr) acur[fr] = cvt8(araw0[fr], araw1[fr]);
  for (int ks = 0; ks < 16; ++ks) {
    if (ks < 15) {
#pragma unroll
      for (int fr = 0; fr < 4; ++fr) {
        araw0[fr] = *(const float4*)&Arow[fr][(ks + 1) * 32];
        araw1[fr] = *(const float4*)&Arow[fr][(ks + 1) * 32 + 4];
      }
#pragma unroll
      for (int cf = 0; cf < 4; ++cf) bnxt[cf] = *(const short8*)&Bb[((ks + 1) * 4 + cf) * 512 + l * 8];
    }
#pragma unroll
    for (int fr = 0; fr < 4; ++fr)
#pragma unroll
      for (int cf = 0; cf < 4; ++cf)
        acc[fr][cf] = __builtin_amdgcn_mfma_f32_16x16x32_bf16(acur[fr], bcur[cf], acc[fr][cf], 0, 0, 0);
    if (ks < 15) {
#pragma unroll
      for (int fr = 0; fr < 4; ++fr) acur[fr] = cvt8(araw0[fr], araw1[fr]);
#pragma unroll
      for (int cf = 0; cf < 4; ++cf) bcur[cf] = bnxt[cf];
    }
  }
  int rowBase = blockIdx.x * 64, colBase = cb * 64;
#pragma unroll
  for (int fr = 0; fr < 4; ++fr)
#pragma unroll
    for (int reg = 0; reg < 4; ++reg) {
      int r = rowBase + fr * 16 + lg * 4 + reg;
      unsigned short* crow = C + r * 1024 + colBase + li;
#pragma unroll
      for (int cf = 0; cf < 4; ++cf) crow[cf * 16] = f2bf(acc[fr][cf][reg]);
    }
}

// ---------------- BN1 stats: both branches per block (512 blocks) -> Part ----------------
__global__ __launch_bounds__(256) void stats_kernel(
    const unsigned short* __restrict__ PQ, const float* __restrict__ a_b1,
    const float* __restrict__ s_b1, float* __restrict__ Part) {
  __shared__ float lbins[4][32];
  int b = blockIdx.x, t = threadIdx.x;
  int w = t >> 6, l = t & 63;
  int half = t >> 7;        // 0 = branch a, 1 = branch s
  int tt = t & 127;
  int c0 = tt * 2;
  int p_off = half ? 512 : 0;
  const unsigned short* base = PQ + b * 10240 + p_off;
  const float* b1h = half ? s_b1 : a_b1;
  float Q0[10], Q1[10];
#pragma unroll
  for (int j = 0; j < 10; ++j) {
    unsigned int qq = *(const unsigned int*)&base[j * 1024 + 256 + c0];
    Q0[j] = bf2f((unsigned short)qq);
    Q1[j] = bf2f((unsigned short)(qq >> 16));
  }
  float sq = 0.f, sq2 = 0.f, qb0 = 0.f, qb1 = 0.f;
#pragma unroll
  for (int j = 0; j < 10; ++j) {
    sq += Q0[j] + Q1[j];
    sq2 += Q0[j] * Q0[j] + Q1[j] * Q1[j];
    qb0 += Q0[j];
    qb1 += Q1[j];
  }
  qb0 *= 0.1f;
  qb1 *= 0.1f;
  float b10 = b1h[c0], b11 = b1h[c0 + 1];
  float r;
  r = wred64(sq);  if (l == 0) lbins[w][0] = r;
  r = wred64(sq2); if (l == 0) lbins[w][1] = r;
#pragma unroll
  for (int i = 0; i < 10; ++i) {
    unsigned int pp = *(const unsigned int*)&base[i * 1024 + c0];
    float P0 = bf2f((unsigned short)pp);
    float P1 = bf2f((unsigned short)(pp >> 16));
    float a0 = P0 + b10, a1 = P1 + b11;
    r = wred64(P0 + P1);                 if (l == 0) lbins[w][2 + i * 3] = r;
    r = wred64(a0 * a0 + a1 * a1);       if (l == 0) lbins[w][3 + i * 3] = r;
    r = wred64(a0 * qb0 + a1 * qb1);     if (l == 0) lbins[w][4 + i * 3] = r;
  }
  __syncthreads();
  if (t < 64) {
    int br = t >> 5, s = t & 31;
    Part[(b * 2 + br) * 32 + s] = lbins[br * 2][s] + lbins[br * 2 + 1][s];
  }
}

// ---------------- reduce partials + BN1 closed-form finalize (grid = 2 branches) ----------------
__global__ void reduce_bn1(const float* __restrict__ Part,
                           const float* __restrict__ a_b1, const float* __restrict__ s_b1,
                           const float* __restrict__ a_g1, const float* __restrict__ a_be1,
                           const float* __restrict__ s_g1, const float* __restrict__ s_be1,
                           float* __restrict__ ST) {
  __shared__ float tmp[256];
  __shared__ float mom[32];
  int br = blockIdx.x, t = threadIdx.x;
  int v = t & 31, c = t >> 5;
  float s = 0.f;
  for (int b = c * 64; b < c * 64 + 64; ++b) s += Part[(b * 2 + br) * 32 + v];
  tmp[t] = s;
  __syncthreads();
  if (t < 32) {
    float m = 0.f;
#pragma unroll
    for (int k = 0; k < 8; ++k) m += tmp[k * 32 + t];
    mom[t] = m;
  }
  __syncthreads();
  if (t < 10) {
    int i = t;
    const float* b1 = br ? s_b1 : a_b1;
    float bsum = 0.f;
    for (int h = 0; h < 256; ++h) bsum += b1[h];
    float meanb1 = bsum * (1.f / 256.f);
    const float invBH = 1.f / (512.f * 256.f);
    const float invBLH = 1.f / (512.f * 10.f * 256.f);
    float SP = mom[2 + i * 3], SA2 = mom[3 + i * 3], SPQ = mom[4 + i * 3];
    float SQ = mom[0], SQ2 = mom[1];
    float mean = SP * invBH + meanb1 + SQ * invBLH;
    float Ez2 = SA2 * invBH + 2.f * SPQ * invBH + SQ2 * invBLH;
    float var = Ez2 - mean * mean;
    float g = br ? s_g1[i] : a_g1[i];
    float be = br ? s_be1[i] : a_be1[i];
    float sc = g / sqrtf(var + 1e-5f);
    ST[64 + br * 20 + i] = sc;
    ST[64 + br * 20 + 10 + i] = be - mean * sc;
  }
}

// ---------------- fused layer2 (R12-best): block = (dialog, i-half, branch) ----------------
// Part2 layout: sum at [(br*10+i)*512 + b], sumsq at [10240 + (br*10+i)*512 + b].
__global__ __launch_bounds__(256, 4) void fused_layer2_half(
    const unsigned short* __restrict__ PQ, const float* __restrict__ ST,
    const float* __restrict__ a_b1, const float* __restrict__ s_b1,
    const unsigned short* __restrict__ W2fa, const unsigned short* __restrict__ W2fs,
    const float* __restrict__ a_b2, const float* __restrict__ s_b2,
    const int* __restrict__ cl, unsigned short* __restrict__ Z2a, unsigned short* __restrict__ Z2s,
    float* __restrict__ Part2) {
  __shared__ __align__(16) unsigned short Atile[64][264];
  __shared__ float bins[10];
  int b = blockIdx.x, half = blockIdx.y, br = blockIdx.z;
  int i0 = half * 5;
  int p_off = br ? 512 : 0;
  const float* b1 = br ? s_b1 : a_b1;
  const unsigned short* W2f = br ? W2fs : W2fa;
  const float* b2 = br ? s_b2 : a_b2;
  unsigned short* Z2out = br ? Z2s : Z2a;
  int sc_off = br ? 84 : 64;
  int t = threadIdx.x;
  int anc = cl[b] - 1;
  if (t < 10) bins[t] = 0.f;
  // ---- early W2/bias prefetch ----
  int w = t >> 6, l = t & 63, li = l & 15, lg = l >> 4;
  int colBase = w * 64;
  const unsigned short* Wb = W2f + w * (8 * 4 * 512);
  short8 bcur[4], bnxt[4];
#pragma unroll
  for (int cf = 0; cf < 4; ++cf) bcur[cf] = *(const short8*)&Wb[(0 * 4 + cf) * 512 + l * 8];
  float b2v[4];
#pragma unroll
  for (int cf = 0; cf < 4; ++cf) b2v[cf] = b2[colBase + cf * 16 + li];
  for (int idx = t; idx < 14 * 264; idx += 256) (&Atile[50][0])[idx] = 0;
  // ---- h1 phase: thread t = column c; bf16 P/Q loads ----
  {
    int c = t;
    float b1c = b1[c];
    float P[5], Q[10];
#pragma unroll
    for (int j = 0; j < 10; ++j) Q[j] = bf2f(PQ[(b * 10 + j) * 1024 + p_off + 256 + c]);
#pragma unroll
    for (int il = 0; il < 5; ++il) P[il] = bf2f(PQ[(b * 10 + i0 + il) * 1024 + p_off + c]);
#pragma unroll
    for (int il = 0; il < 5; ++il) {
      float sc = ST[sc_off + i0 + il], sh = ST[sc_off + 10 + i0 + il];
      float base = (P[il] + b1c) * sc + sh;
#pragma unroll
      for (int j = 0; j < 10; ++j) {
        float z = base + Q[j] * sc;
        float h;
        if (br) {
          float ex = __expf(2.f * z);
          h = 1.f - 2.f / (ex + 1.f);
        } else {
          h = fmaxf(z, 0.f);
        }
        Atile[il * 10 + j][c] = f2bf(h);
      }
    }
  }
  __syncthreads();
  // ---- MFMA: wave w owns 64 cols, 64 rows (50 valid); W2 frags coalesced + prefetched ----
  f32x4 acc[4][4] = {};
  for (int ks = 0; ks < 8; ++ks) {
    if (ks < 7) {
#pragma unroll
      for (int cf = 0; cf < 4; ++cf) bnxt[cf] = *(const short8*)&Wb[((ks + 1) * 4 + cf) * 512 + l * 8];
    }
    int ka = ks * 32 + lg * 8;
#pragma unroll
    for (int fr = 0; fr < 4; ++fr) {
      short8 afr = *(const short8*)&Atile[fr * 16 + li][ka];
#pragma unroll
      for (int cf = 0; cf < 4; ++cf)
        acc[fr][cf] = __builtin_amdgcn_mfma_f32_16x16x32_bf16(afr, bcur[cf], acc[fr][cf], 0, 0, 0);
    }
#pragma unroll
    for (int cf = 0; cf < 4; ++cf) bcur[cf] = bnxt[cf];
  }
  // ---- epilogue: bias, anchor-row writes (bf16), BN2 bins (LDS only) ----
#pragma unroll
  for (int fr = 0; fr < 4; ++fr) {
#pragma unroll
    for (int reg = 0; reg < 4; ++reg) {
      int row = fr * 16 + lg * 4 + reg;
      bool valid = row < 50;
      int il = row / 10, jj = row - il * 10;
      float z0 = acc[fr][0][reg] + b2v[0];
      float z1 = acc[fr][1][reg] + b2v[1];
      float z2 = acc[fr][2][reg] + b2v[2];
      float z3 = acc[fr][3][reg] + b2v[3];
      if (valid && (i0 + il) == anc) {
        unsigned short* dst = Z2out + (b * 10 + jj) * 256 + colBase + li;
        dst[0] = f2bf(z0); dst[16] = f2bf(z1); dst[32] = f2bf(z2); dst[48] = f2bf(z3);
      }
      float s = valid ? (z0 + z1 + z2 + z3) : 0.f;
      float q = valid ? (z0 * z0 + z1 * z1 + z2 * z2 + z3 * z3) : 0.f;
#pragma unroll
      for (int o = 1; o < 16; o <<= 1) {
        s += __shfl_xor(s, o);
        q += __shfl_xor(q, o);
      }
      if (li == 0 && valid) {
        atomicAdd(&bins[il], s);
        atomicAdd(&bins[5 + il], q);
      }
    }
  }
  __syncthreads();
  if (t < 5) {
    Part2[(br * 10 + i0 + t) * 512 + b] = bins[t];
    Part2[10240 + (br * 10 + i0 + t) * 512 + b] = bins[5 + t];
  }
}

// ---------------- merged GRU GEMMs: grid (16, 3, 2), N=768 ----------------
__global__ __launch_bounds__(256) void gemm_gru2(
    const unsigned short* __restrict__ A0, const unsigned short* __restrict__ B0,
    float* __restrict__ C0, const float* __restrict__ bias0,
    const unsigned short* __restrict__ A1, const unsigned short* __restrict__ B1,
    float* __restrict__ C1, const float* __restrict__ bias1) {
  const unsigned short* A; const unsigned short* Bw; float* C; const float* bias; int K;
  if (blockIdx.z == 0) { A = A0; Bw = B0; C = C0; bias = bias0; K = 512; }
  else                 { A = A1; Bw = B1; C = C1; bias = bias1; K = 256; }
  int t = threadIdx.x;
  int w = t >> 6, l = t & 63, li = l & 15, lg = l >> 4;
  int rowBase = blockIdx.x * 32;
  int colBase = blockIdx.y * 256 + w * 64;
  f32x4 acc[2][4] = {};
  const unsigned short* Arow[2];
  const unsigned short* Brow[4];
#pragma unroll
  for (int fr = 0; fr < 2; ++fr) Arow[fr] = A + (rowBase + fr * 16 + li) * K;
#pragma unroll
  for (int cf = 0; cf < 4; ++cf) Brow[cf] = Bw + (colBase + cf * 16 + li) * K;
  for (int ks = 0; ks < K / 32; ++ks) {
    int ka = ks * 32 + lg * 8;
    short8 afr[2], bfr[4];
#pragma unroll
    for (int fr = 0; fr < 2; ++fr) afr[fr] = *(const short8*)&Arow[fr][ka];
#pragma unroll
    for (int cf = 0; cf < 4; ++cf) bfr[cf] = *(const short8*)&Brow[cf][ka];
#pragma unroll
    for (int fr = 0; fr < 2; ++fr)
#pragma unroll
      for (int cf = 0; cf < 4; ++cf)
        acc[fr][cf] = __builtin_amdgcn_mfma_f32_16x16x32_bf16(afr[fr], bfr[cf], acc[fr][cf], 0, 0, 0);
  }
  float b2v[4];
#pragma unroll
  for (int cf = 0; cf < 4; ++cf) b2v[cf] = bias[colBase + cf * 16 + li];
#pragma unroll
  for (int fr = 0; fr < 2; ++fr)
#pragma unroll
    for (int reg = 0; reg < 4; ++reg) {
      int r = rowBase + fr * 16 + lg * 4 + reg;
      float* crow = C + r * 768 + colBase + li;
#pragma unroll
      for (int cf = 0; cf < 4; ++cf) crow[cf * 16] = acc[fr][cf][reg] + b2v[cf];
    }
}

// ---------------- postproc: BN2 finalize (anchor-only) + wave-parallel j-dots ----------------
__global__ __launch_bounds__(256) void postproc_kernel(
    const float* __restrict__ Part2,
    const float* __restrict__ a_g2, const float* __restrict__ a_be2,
    const float* __restrict__ s_g2, const float* __restrict__ s_be2,
    const unsigned short* __restrict__ Z2a, const unsigned short* __restrict__ Z2s,
    const float* __restrict__ a_w3, const float* __restrict__ a_b3,
    const float* __restrict__ mu_w, const float* __restrict__ mu_b,
    const float* __restrict__ sg_w, const float* __restrict__ sg_b,
    const float* __restrict__ aij_eps, const float* __restrict__ sij_eps,
    const int* __restrict__ cl, const float* __restrict__ utt,
    unsigned short* __restrict__ msgbf, unsigned short* __restrict__ h0bf,
    float* __restrict__ h0out) {
  int b = blockIdx.x, t = threadIdx.x;
  int w = t >> 6, l = t & 63;
  int a = cl[b] - 1;
  __shared__ float bn2r[4];
  {
    int p = (w >> 1) * 10 + a;
    int off = (w & 1) ? 10240 : 0;
    float s = 0.f;
#pragma unroll
    for (int k = 0; k < 8; ++k) s += Part2[off + p * 512 + l + k * 64];
    s = wred64(s);
    if (l == 0) bn2r[w] = s;
  }
  __syncthreads();
  __shared__ float sc2[4];  // sc2a, sh2a, sc2s, sh2s
  if (t < 2) {
    int br = t;
    const float invN = 1.f / (512.f * 10.f * 256.f);
    float m = bn2r[br * 2 + 0] * invN;
    float v = bn2r[br * 2 + 1] * invN - m * m;
    float g = br ? s_g2[a] : a_g2[a];
    float be = br ? s_be2[a] : a_be2[a];
    float sc = g / sqrtf(v + 1e-5f);
    sc2[br * 2] = sc;
    sc2[br * 2 + 1] = be - m * sc;
  }
  __syncthreads();
  float sc2a = sc2[0], sh2a = sc2[1], sc2s = sc2[2], sh2s = sc2[3];
  __shared__ float red[30];
#pragma unroll
  for (int m = 0; m < 3; ++m) {
    int j = w + 4 * m;
    if (j < 10) {
      float pa = 0.f, pm = 0.f, ps = 0.f;
#pragma unroll
      for (int cc = 0; cc < 4; ++cc) {
        int c = l + cc * 64;
        float za = bf2f(Z2a[(b * 10 + j) * 256 + c]);
        float va = fmaxf(za * sc2a + sh2a, 0.f);
        float zs = bf2f(Z2s[(b * 10 + j) * 256 + c]);
        float vs = tanh_fast(zs * sc2s + sh2s);
        pa += va * a_w3[c];
        pm += vs * mu_w[c];
        ps += vs * sg_w[c];
      }
      pa = wred64(pa); pm = wred64(pm); ps = wred64(ps);
      if (l == 0) { red[j] = pa; red[10 + j] = pm; red[20 + j] = ps; }
    }
  }
  __syncthreads();
  __shared__ float pw[10];
  __shared__ float wijs[16];
  if (t < 10) {
    int j = t;
    float amij = red[j] + a_b3[0];
    float amu = softplusf(amij) + 0.01f;
    float astd = sqrtf(softplusf((1.f - amu) * amu) + 0.01f);
    float ae = aij_eps[b * 100 + a * 10 + j];
    float aij = softplusf(ae * astd + amu) + 0.01f;
    float smu = red[10 + j] + mu_b[0];
    float ssg = red[20 + j] + sg_b[0];
    float se = sij_eps[b * 100 + a * 10 + j];
    float sij = se * sqrtf(aij * ssg * ssg) + aij * smu;
    wijs[j] = aij * sij;
  }
  __syncthreads();
  if (t == 0) {
    float mx = -1e30f;
    for (int j = 0; j < a; ++j) mx = fmaxf(mx, wijs[j]);
    float e[10];
    float den = 0.f;
    for (int j = 0; j < a; ++j) { e[j] = __expf(wijs[j] - mx); den += e[j]; }
    for (int j = 0; j < 10; ++j) pw[j] = (j < a) ? e[j] / den : 0.f;
  }
  __syncthreads();
#pragma unroll
  for (int dd = 0; dd < 2; ++dd) {
    int d = t + dd * 256;
    float mv = 0.f;
#pragma unroll
    for (int j = 0; j < 10; ++j) mv += pw[j] * utt[(b * 10 + j) * 512 + d];
    msgbf[b * 512 + d] = f2bf(mv);
  }
  float u1 = utt[(b * 10 + a) * 512 + t];
  float u2 = utt[(b * 10 + a) * 512 + 256 + t];
  float h0v = u1 + u2;
  h0out[b * 256 + t] = h0v;
  h0bf[b * 256 + t] = f2bf(h0v);
}

// ---------------- GRU elementwise (fast transcendentals) ----------------
__global__ __launch_bounds__(256) void gru_final(const float* __restrict__ gi,
                                                 const float* __restrict__ gh,
                                                 const float* __restrict__ h0,
                                                 float* __restrict__ out) {
  int idx = blockIdx.x * 256 + threadIdx.x;
  int b = idx >> 8, h = idx & 255;
  float ir = gi[b * 768 + h], iz = gi[b * 768 + 256 + h], inn = gi[b * 768 + 512 + h];
  float hr = gh[b * 768 + h], hz = gh[b * 768 + 256 + h], hn = gh[b * 768 + 512 + h];
  float r = sigmoid_fast(ir + hr);
  float z = sigmoid_fast(iz + hz);
  float n = tanh_fast(inn + r * hn);
  out[idx] = (1.f - z) * n + z * h0[b * 256 + h];
}

extern "C" void kernel_launch(void* const* d_in, const int* in_sizes, int n_in,
                              void* d_out, int out_size, void* d_ws, size_t ws_size,
                              hipStream_t stream) {
  const float* utt = (const float*)d_in[0];
  const float* aij_eps = (const float*)d_in[1];
  const float* sij_eps = (const float*)d_in[2];
  const int* cl = (const int*)d_in[3];
  const float* a_w1 = (const float*)d_in[4];
  const float* a_b1 = (const float*)d_in[5];
  const float* a_g1 = (const float*)d_in[6];
  const float* a_be1 = (const float*)d_in[7];
  const float* a_w2 = (const float*)d_in[8];
  const float* a_b2 = (const float*)d_in[9];
  const float* a_g2 = (const float*)d_in[10];
  const float* a_be2 = (const float*)d_in[11];
  const float* a_w3 = (const float*)d_in[12];
  const float* a_b3 = (const float*)d_in[13];
  const float* s_w1 = (const float*)d_in[14];
  const float* s_b1 = (const float*)d_in[15];
  const float* s_g1 = (const float*)d_in[16];
  const float* s_be1 = (const float*)d_in[17];
  const float* s_w2 = (const float*)d_in[18];
  const float* s_b2 = (const float*)d_in[19];
  const float* s_g2 = (const float*)d_in[20];
  const float* s_be2 = (const float*)d_in[21];
  const float* mu_w = (const float*)d_in[22];
  const float* mu_b = (const float*)d_in[23];
  const float* sg_w = (const float*)d_in[24];
  const float* sg_b = (const float*)d_in[25];
  const float* gru_wi = (const float*)d_in[26];
  const float* gru_wh = (const float*)d_in[27];
  const float* gru_bi = (const float*)d_in[28];
  const float* gru_bh = (const float*)d_in[29];

  float* ws = (float*)d_ws;
  float* ST = ws;                                            // 256 floats
  unsigned short* hole = (unsigned short*)(ws + 256);        // (layout hole)
  unsigned short* Bf = hole + 2621440;                       // 524288 sh
  unsigned short* W2fa = Bf + 524288;                        // 65536 sh
  unsigned short* W2fs = W2fa + 65536;                       // 65536 sh
  unsigned short* wibf = W2fs + 65536;                       // 393216 sh
  unsigned short* whbf = wibf + 393216;                      // 196608 sh
  float* PQf = (float*)(whbf + 196608);                      // region: 5242880 f (PQ bf16 uses half)
  unsigned short* PQ = (unsigned short*)PQf;                 // 5242880 sh used
  unsigned short* Z2a = (unsigned short*)(PQf + 5242880);    // 1310720 sh
  unsigned short* Z2s = Z2a + 1310720;                       // 1310720 sh
  float* Part = PQf + 5242880 + 1310720;                     // 32768 f
  float* Part2 = Part + 32768;                               // 20480 f
  // postproc/GRU buffers alias the tail of the PQ region (PQ bf16 occupies first half only)
  float* tailf = PQf + 2621440;                              // 2621440 f free
  unsigned short* msgbf = (unsigned short*)tailf;            // 262144 sh
  unsigned short* h0bf = msgbf + 262144;                     // 131072 sh
  float* h0 = tailf + 196608;                                // 131072 f
  float* gi = tailf + 327680;                                // 393216 f
  float* gh = gi + 393216;                                   // 393216 f

  prep_weights<<<608, 256, 0, stream>>>(a_w1, s_w1, a_w2, s_w2, gru_wi, gru_wh,
                                        Bf, W2fa, W2fs, wibf, whbf);
  gemm_pq_swz<<<dim3(80, 4), 256, 0, stream>>>(utt, Bf, PQ);
  stats_kernel<<<512, 256, 0, stream>>>(PQ, a_b1, s_b1, Part);
  reduce_bn1<<<2, 256, 0, stream>>>(Part, a_b1, s_b1, a_g1, a_be1, s_g1, s_be1, ST);
  fused_layer2_half<<<dim3(512, 2, 2), 256, 0, stream>>>(PQ, ST, a_b1, s_b1, W2fa, W2fs,
                                                         a_b2, s_b2, cl, Z2a, Z2s, Part2);
  postproc_kernel<<<512, 256, 0, stream>>>(Part2, a_g2, a_be2, s_g2, s_be2,
                                           Z2a, Z2s, a_w3, a_b3, mu_w, mu_b, sg_w, sg_b,
                                           aij_eps, sij_eps, cl, utt, msgbf, h0bf, h0);
  gemm_gru2<<<dim3(16, 3, 2), 256, 0, stream>>>(msgbf, wibf, gi, gru_bi,
                                                h0bf, whbf, gh, gru_bh);
  gru_final<<<512, 256, 0, stream>>>(gi, gh, h0, (float*)d_out);
}

// Round 18
// 112.883 us; speedup vs baseline: 1.3651x; 1.1955x over previous
//
#include <hip/hip_runtime.h>
#include <math.h>

// ContextEncoder: B=512, L=10, H=256, D=512.  (R15-best configuration, measured 113.1 us)
//  prep: VECTORIZED bf16 conversions (short8/thread, float4 reads); MFMA fragment order.
//  gemm_pq_swz: 64x256 tile, swizzled bf16 operands, reg dbuf k-loop, bf16 out.
//  stats_kernel: BOTH branches per block (512 blocks), uint bf16-pair loads -> Part.
//  reduce_bn1: BN1 closed-form from partials (separate 2-block dispatch; R16 lesson:
//    last-block __threadfence pattern costs ~50us on 8-XCD MI355X).
//  fused_layer2_half: R12-best config (512x2x2, one branch/block, VGPR 64), bf16 Z2, Part2.
//  postproc: BN2 finalize (anchor-only) + wave-parallel j-dots, fast transcendentals.
//  gemm_gru2 (both GRU GEMMs), gru_final. 8 dispatches.
//  R13 lesson: merging fused branches spills acc to scratch.
//  R17 lesson: in-register fp32->bf16 convert inside the GEMM k-loop serializes with MFMA —
//    staging conversions in prep (bandwidth-cheap, parallel) is faster.

typedef __attribute__((ext_vector_type(8))) short short8;
typedef __attribute__((ext_vector_type(4))) float f32x4;

__device__ __forceinline__ float softplusf(float x) {
  return x > 0.f ? x + log1pf(expf(-x)) : log1pf(expf(x));
}
__device__ __forceinline__ float wred64(float v) {
#pragma unroll
  for (int o = 32; o > 0; o >>= 1) v += __shfl_down(v, o);
  return v;
}
__device__ __forceinline__ unsigned short f2bf(float f) {
  unsigned int u = __float_as_uint(f);
  u += 0x7fffu + ((u >> 16) & 1u);
  return (unsigned short)(u >> 16);
}
__device__ __forceinline__ float bf2f(unsigned short u) {
  return __uint_as_float(((unsigned int)u) << 16);
}
__device__ __forceinline__ float tanh_fast(float x) {
  float ex = __expf(2.f * x);
  return 1.f - 2.f / (ex + 1.f);
}
__device__ __forceinline__ float sigmoid_fast(float x) {
  return 1.f / (1.f + __expf(-x));
}
__device__ __forceinline__ short8 pack8(const float* __restrict__ p) {
  float4 v0 = *(const float4*)p;
  float4 v1 = *(const float4*)(p + 4);
  short8 r;
  r[0] = (short)f2bf(v0.x); r[1] = (short)f2bf(v0.y);
  r[2] = (short)f2bf(v0.z); r[3] = (short)f2bf(v0.w);
  r[4] = (short)f2bf(v1.x); r[5] = (short)f2bf(v1.y);
  r[6] = (short)f2bf(v1.z); r[7] = (short)f2bf(v1.w);
  return r;
}

// ---------------- prep: vectorized bf16 conversions + fragment-order swizzles ----------------
__global__ __launch_bounds__(256) void prep_weights(
    const float* __restrict__ utt,
    const float* __restrict__ a_w1, const float* __restrict__ s_w1,
    const float* __restrict__ a_w2, const float* __restrict__ s_w2,
    const float* __restrict__ gru_wi, const float* __restrict__ gru_wh,
    unsigned short* __restrict__ Af, unsigned short* __restrict__ Bf,
    unsigned short* __restrict__ W2fa, unsigned short* __restrict__ W2fs,
    unsigned short* __restrict__ wibf, unsigned short* __restrict__ whbf) {
  int i = blockIdx.x * 256 + threadIdx.x;
  if (i < 327680) {  // Af: i = rb*1024 + ks*64 + lane
    int lane = i & 63, ks = (i >> 6) & 15, rb = i >> 10;
    int row = rb * 16 + (lane & 15);
    int k = ks * 32 + (lane >> 4) * 8;
    *(short8*)&Af[i * 8] = pack8(&utt[row * 512 + k]);
    return;
  }
  i -= 327680;
  if (i < 65536) {  // Bf: i = cb*4096 + ks*256 + cf*64 + lane
    int lane = i & 63, cf = (i >> 6) & 3, ks = (i >> 8) & 15, cb = i >> 12;
    int c = cb * 64 + cf * 16 + (lane & 15);
    int k = ks * 32 + (lane >> 4) * 8;
    const float* src;
    if (c < 256)       src = &a_w1[c * 1024 + k];
    else if (c < 512)  src = &a_w1[(c - 256) * 1024 + 512 + k];
    else if (c < 768)  src = &s_w1[(c - 512) * 1024 + k];
    else               src = &s_w1[(c - 768) * 1024 + 512 + k];
    *(short8*)&Bf[i * 8] = pack8(src);
    return;
  }
  i -= 65536;
  if (i < 8192) {  // W2fa: i = cb*2048 + ks*256 + cf*64 + lane
    int lane = i & 63, cf = (i >> 6) & 3, ks = (i >> 8) & 7, cb = i >> 11;
    int c = cb * 64 + cf * 16 + (lane & 15);
    int k = ks * 32 + (lane >> 4) * 8;
    *(short8*)&W2fa[i * 8] = pack8(&a_w2[c * 256 + k]);
    return;
  }
  i -= 8192;
  if (i < 8192) {  // W2fs
    int lane = i & 63, cf = (i >> 6) & 3, ks = (i >> 8) & 7, cb = i >> 11;
    int c = cb * 64 + cf * 16 + (lane & 15);
    int k = ks * 32 + (lane >> 4) * 8;
    *(short8*)&W2fs[i * 8] = pack8(&s_w2[c * 256 + k]);
    return;
  }
  i -= 8192;
  if (i < 49152) { *(short8*)&wibf[i * 8] = pack8(&gru_wi[i * 8]); return; }
  i -= 49152;
  *(short8*)&whbf[i * 8] = pack8(&gru_wh[i * 8]);
}

// ---------------- PQ GEMM (bf16 out), 64x256 tile, swizzled operands, reg dbuf ----------------
__global__ __launch_bounds__(256) void gemm_pq_swz(
    const unsigned short* __restrict__ Af, const unsigned short* __restrict__ Bf,
    unsigned short* __restrict__ C) {
  int t = threadIdx.x;
  int w = t >> 6, l = t & 63, li = l & 15, lg = l >> 4;
  int rb0 = blockIdx.x * 4;
  int cb = blockIdx.y * 4 + w;
  const unsigned short* Bb = Bf + cb * (16 * 4 * 512);
  f32x4 acc[4][4] = {};
  short8 acur[4], bcur[4], anxt[4], bnxt[4];
#pragma unroll
  for (int fr = 0; fr < 4; ++fr) acur[fr] = *(const short8*)&Af[((rb0 + fr) * 16 + 0) * 512 + l * 8];
#pragma unroll
  for (int cf = 0; cf < 4; ++cf) bcur[cf] = *(const short8*)&Bb[(0 * 4 + cf) * 512 + l * 8];
  for (int ks = 0; ks < 16; ++ks) {
    if (ks < 15) {
#pragma unroll
      for (int fr = 0; fr < 4; ++fr) anxt[fr] = *(const short8*)&Af[((rb0 + fr) * 16 + ks + 1) * 512 + l * 8];
#pragma unroll
      for (int cf = 0; cf < 4; ++cf) bnxt[cf] = *(const short8*)&Bb[((ks + 1) * 4 + cf) * 512 + l * 8];
    }
#pragma unroll
    for (int fr = 0; fr < 4; ++fr)
#pragma unroll
      for (int cf = 0; cf < 4; ++cf)
        acc[fr][cf] = __builtin_amdgcn_mfma_f32_16x16x32_bf16(acur[fr], bcur[cf], acc[fr][cf], 0, 0, 0);
#pragma unroll
    for (int fr = 0; fr < 4; ++fr) acur[fr] = anxt[fr];
#pragma unroll
    for (int cf = 0; cf < 4; ++cf) bcur[cf] = bnxt[cf];
  }
  int rowBase = blockIdx.x * 64, colBase = cb * 64;
#pragma unroll
  for (int fr = 0; fr < 4; ++fr)
#pragma unroll
    for (int reg = 0; reg < 4; ++reg) {
      int r = rowBase + fr * 16 + lg * 4 + reg;
      unsigned short* crow = C + r * 1024 + colBase + li;
#pragma unroll
      for (int cf = 0; cf < 4; ++cf) crow[cf * 16] = f2bf(acc[fr][cf][reg]);
    }
}

// ---------------- BN1 stats: BOTH branches per block (512 blocks), uint pair loads ----------------
__global__ __launch_bounds__(256) void stats_kernel(
    const unsigned short* __restrict__ PQ, const float* __restrict__ a_b1,
    const float* __restrict__ s_b1, float* __restrict__ Part) {
  __shared__ float lbins[4][32];
  int b = blockIdx.x, t = threadIdx.x;
  int w = t >> 6, l = t & 63;
  int half = t >> 7;        // 0 = branch a, 1 = branch s
  int tt = t & 127;
  int c0 = tt * 2;
  int p_off = half ? 512 : 0;
  const unsigned short* base = PQ + b * 10240 + p_off;
  const float* b1 = half ? s_b1 : a_b1;
  float Q0[10], Q1[10];
#pragma unroll
  for (int j = 0; j < 10; ++j) {
    unsigned int qq = *(const unsigned int*)&base[j * 1024 + 256 + c0];
    Q0[j] = bf2f((unsigned short)qq);
    Q1[j] = bf2f((unsigned short)(qq >> 16));
  }
  float sq = 0.f, sq2 = 0.f, qb0 = 0.f, qb1 = 0.f;
#pragma unroll
  for (int j = 0; j < 10; ++j) {
    sq += Q0[j] + Q1[j];
    sq2 += Q0[j] * Q0[j] + Q1[j] * Q1[j];
    qb0 += Q0[j];
    qb1 += Q1[j];
  }
  qb0 *= 0.1f;
  qb1 *= 0.1f;
  float b10 = b1[c0], b11 = b1[c0 + 1];
  float r;
  r = wred64(sq);  if (l == 0) lbins[w][0] = r;
  r = wred64(sq2); if (l == 0) lbins[w][1] = r;
#pragma unroll
  for (int i = 0; i < 10; ++i) {
    unsigned int pp = *(const unsigned int*)&base[i * 1024 + c0];
    float P0 = bf2f((unsigned short)pp);
    float P1 = bf2f((unsigned short)(pp >> 16));
    float a0 = P0 + b10, a1 = P1 + b11;
    r = wred64(P0 + P1);                 if (l == 0) lbins[w][2 + i * 3] = r;
    r = wred64(a0 * a0 + a1 * a1);       if (l == 0) lbins[w][3 + i * 3] = r;
    r = wred64(a0 * qb0 + a1 * qb1);     if (l == 0) lbins[w][4 + i * 3] = r;
  }
  __syncthreads();
  if (t < 64) {
    int br = t >> 5, s = t & 31;
    Part[(b * 2 + br) * 32 + s] = lbins[br * 2][s] + lbins[br * 2 + 1][s];
  }
}

// ---------------- reduce partials + BN1 closed-form finalize (grid = 2 branches) ----------------
__global__ void reduce_bn1(const float* __restrict__ Part,
                           const float* __restrict__ a_b1, const float* __restrict__ s_b1,
                           const float* __restrict__ a_g1, const float* __restrict__ a_be1,
                           const float* __restrict__ s_g1, const float* __restrict__ s_be1,
                           float* __restrict__ ST) {
  __shared__ float tmp[256];
  __shared__ float mom[32];
  int br = blockIdx.x, t = threadIdx.x;
  int v = t & 31, c = t >> 5;
  float s = 0.f;
  for (int b = c * 64; b < c * 64 + 64; ++b) s += Part[(b * 2 + br) * 32 + v];
  tmp[t] = s;
  __syncthreads();
  if (t < 32) {
    float m = 0.f;
#pragma unroll
    for (int k = 0; k < 8; ++k) m += tmp[k * 32 + t];
    mom[t] = m;
  }
  __syncthreads();
  if (t < 10) {
    int i = t;
    const float* b1 = br ? s_b1 : a_b1;
    float bsum = 0.f;
    for (int h = 0; h < 256; ++h) bsum += b1[h];
    float meanb1 = bsum * (1.f / 256.f);
    const float invBH = 1.f / (512.f * 256.f);
    const float invBLH = 1.f / (512.f * 10.f * 256.f);
    float SP = mom[2 + i * 3], SA2 = mom[3 + i * 3], SPQ = mom[4 + i * 3];
    float SQ = mom[0], SQ2 = mom[1];
    float mean = SP * invBH + meanb1 + SQ * invBLH;
    float Ez2 = SA2 * invBH + 2.f * SPQ * invBH + SQ2 * invBLH;
    float var = Ez2 - mean * mean;
    float g = br ? s_g1[i] : a_g1[i];
    float be = br ? s_be1[i] : a_be1[i];
    float sc = g / sqrtf(var + 1e-5f);
    ST[64 + br * 20 + i] = sc;
    ST[64 + br * 20 + 10 + i] = be - mean * sc;
  }
}

// ---------------- fused layer2 (R12-best): block = (dialog, i-half, branch) ----------------
// Part2 layout: sum at [(br*10+i)*512 + b], sumsq at [10240 + (br*10+i)*512 + b].
__global__ __launch_bounds__(256, 4) void fused_layer2_half(
    const unsigned short* __restrict__ PQ, const float* __restrict__ ST,
    const float* __restrict__ a_b1, const float* __restrict__ s_b1,
    const unsigned short* __restrict__ W2fa, const unsigned short* __restrict__ W2fs,
    const float* __restrict__ a_b2, const float* __restrict__ s_b2,
    const int* __restrict__ cl, unsigned short* __restrict__ Z2a, unsigned short* __restrict__ Z2s,
    float* __restrict__ Part2) {
  __shared__ __align__(16) unsigned short Atile[64][264];
  __shared__ float bins[10];
  int b = blockIdx.x, half = blockIdx.y, br = blockIdx.z;
  int i0 = half * 5;
  int p_off = br ? 512 : 0;
  const float* b1 = br ? s_b1 : a_b1;
  const unsigned short* W2f = br ? W2fs : W2fa;
  const float* b2 = br ? s_b2 : a_b2;
  unsigned short* Z2out = br ? Z2s : Z2a;
  int sc_off = br ? 84 : 64;
  int t = threadIdx.x;
  int anc = cl[b] - 1;
  if (t < 10) bins[t] = 0.f;
  // ---- early W2/bias prefetch ----
  int w = t >> 6, l = t & 63, li = l & 15, lg = l >> 4;
  int colBase = w * 64;
  const unsigned short* Wb = W2f + w * (8 * 4 * 512);
  short8 bcur[4], bnxt[4];
#pragma unroll
  for (int cf = 0; cf < 4; ++cf) bcur[cf] = *(const short8*)&Wb[(0 * 4 + cf) * 512 + l * 8];
  float b2v[4];
#pragma unroll
  for (int cf = 0; cf < 4; ++cf) b2v[cf] = b2[colBase + cf * 16 + li];
  for (int idx = t; idx < 14 * 264; idx += 256) (&Atile[50][0])[idx] = 0;
  // ---- h1 phase: thread t = column c; bf16 P/Q loads ----
  {
    int c = t;
    float b1c = b1[c];
    float P[5], Q[10];
#pragma unroll
    for (int j = 0; j < 10; ++j) Q[j] = bf2f(PQ[(b * 10 + j) * 1024 + p_off + 256 + c]);
#pragma unroll
    for (int il = 0; il < 5; ++il) P[il] = bf2f(PQ[(b * 10 + i0 + il) * 1024 + p_off + c]);
#pragma unroll
    for (int il = 0; il < 5; ++il) {
      float sc = ST[sc_off + i0 + il], sh = ST[sc_off + 10 + i0 + il];
      float base = (P[il] + b1c) * sc + sh;
#pragma unroll
      for (int j = 0; j < 10; ++j) {
        float z = base + Q[j] * sc;
        float h;
        if (br) {
          float ex = __expf(2.f * z);
          h = 1.f - 2.f / (ex + 1.f);
        } else {
          h = fmaxf(z, 0.f);
        }
        Atile[il * 10 + j][c] = f2bf(h);
      }
    }
  }
  __syncthreads();
  // ---- MFMA: wave w owns 64 cols, 64 rows (50 valid); W2 frags coalesced + prefetched ----
  f32x4 acc[4][4] = {};
  for (int ks = 0; ks < 8; ++ks) {
    if (ks < 7) {
#pragma unroll
      for (int cf = 0; cf < 4; ++cf) bnxt[cf] = *(const short8*)&Wb[((ks + 1) * 4 + cf) * 512 + l * 8];
    }
    int ka = ks * 32 + lg * 8;
#pragma unroll
    for (int fr = 0; fr < 4; ++fr) {
      short8 afr = *(const short8*)&Atile[fr * 16 + li][ka];
#pragma unroll
      for (int cf = 0; cf < 4; ++cf)
        acc[fr][cf] = __builtin_amdgcn_mfma_f32_16x16x32_bf16(afr, bcur[cf], acc[fr][cf], 0, 0, 0);
    }
#pragma unroll
    for (int cf = 0; cf < 4; ++cf) bcur[cf] = bnxt[cf];
  }
  // ---- epilogue: bias, anchor-row writes (bf16), BN2 bins (LDS only) ----
#pragma unroll
  for (int fr = 0; fr < 4; ++fr) {
#pragma unroll
    for (int reg = 0; reg < 4; ++reg) {
      int row = fr * 16 + lg * 4 + reg;
      bool valid = row < 50;
      int il = row / 10, jj = row - il * 10;
      float z0 = acc[fr][0][reg] + b2v[0];
      float z1 = acc[fr][1][reg] + b2v[1];
      float z2 = acc[fr][2][reg] + b2v[2];
      float z3 = acc[fr][3][reg] + b2v[3];
      if (valid && (i0 + il) == anc) {
        unsigned short* dst = Z2out + (b * 10 + jj) * 256 + colBase + li;
        dst[0] = f2bf(z0); dst[16] = f2bf(z1); dst[32] = f2bf(z2); dst[48] = f2bf(z3);
      }
      float s = valid ? (z0 + z1 + z2 + z3) : 0.f;
      float q = valid ? (z0 * z0 + z1 * z1 + z2 * z2 + z3 * z3) : 0.f;
#pragma unroll
      for (int o = 1; o < 16; o <<= 1) {
        s += __shfl_xor(s, o);
        q += __shfl_xor(q, o);
      }
      if (li == 0 && valid) {
        atomicAdd(&bins[il], s);
        atomicAdd(&bins[5 + il], q);
      }
    }
  }
  __syncthreads();
  if (t < 5) {
    Part2[(br * 10 + i0 + t) * 512 + b] = bins[t];
    Part2[10240 + (br * 10 + i0 + t) * 512 + b] = bins[5 + t];
  }
}

// ---------------- merged GRU GEMMs: grid (16, 3, 2), N=768 ----------------
__global__ __launch_bounds__(256) void gemm_gru2(
    const unsigned short* __restrict__ A0, const unsigned short* __restrict__ B0,
    float* __restrict__ C0, const float* __restrict__ bias0,
    const unsigned short* __restrict__ A1, const unsigned short* __restrict__ B1,
    float* __restrict__ C1, const float* __restrict__ bias1) {
  const unsigned short* A; const unsigned short* Bw; float* C; const float* bias; int K;
  if (blockIdx.z == 0) { A = A0; Bw = B0; C = C0; bias = bias0; K = 512; }
  else                 { A = A1; Bw = B1; C = C1; bias = bias1; K = 256; }
  int t = threadIdx.x;
  int w = t >> 6, l = t & 63, li = l & 15, lg = l >> 4;
  int rowBase = blockIdx.x * 32;
  int colBase = blockIdx.y * 256 + w * 64;
  f32x4 acc[2][4] = {};
  const unsigned short* Arow[2];
  const unsigned short* Brow[4];
#pragma unroll
  for (int fr = 0; fr < 2; ++fr) Arow[fr] = A + (rowBase + fr * 16 + li) * K;
#pragma unroll
  for (int cf = 0; cf < 4; ++cf) Brow[cf] = Bw + (colBase + cf * 16 + li) * K;
  for (int ks = 0; ks < K / 32; ++ks) {
    int ka = ks * 32 + lg * 8;
    short8 afr[2], bfr[4];
#pragma unroll
    for (int fr = 0; fr < 2; ++fr) afr[fr] = *(const short8*)&Arow[fr][ka];
#pragma unroll
    for (int cf = 0; cf < 4; ++cf) bfr[cf] = *(const short8*)&Brow[cf][ka];
#pragma unroll
    for (int fr = 0; fr < 2; ++fr)
#pragma unroll
      for (int cf = 0; cf < 4; ++cf)
        acc[fr][cf] = __builtin_amdgcn_mfma_f32_16x16x32_bf16(afr[fr], bfr[cf], acc[fr][cf], 0, 0, 0);
  }
  float b2v[4];
#pragma unroll
  for (int cf = 0; cf < 4; ++cf) b2v[cf] = bias[colBase + cf * 16 + li];
#pragma unroll
  for (int fr = 0; fr < 2; ++fr)
#pragma unroll
    for (int reg = 0; reg < 4; ++reg) {
      int r = rowBase + fr * 16 + lg * 4 + reg;
      float* crow = C + r * 768 + colBase + li;
#pragma unroll
      for (int cf = 0; cf < 4; ++cf) crow[cf * 16] = acc[fr][cf][reg] + b2v[cf];
    }
}

// ---------------- postproc: BN2 finalize (anchor-only) + wave-parallel j-dots ----------------
__global__ __launch_bounds__(256) void postproc_kernel(
    const float* __restrict__ Part2,
    const float* __restrict__ a_g2, const float* __restrict__ a_be2,
    const float* __restrict__ s_g2, const float* __restrict__ s_be2,
    const unsigned short* __restrict__ Z2a, const unsigned short* __restrict__ Z2s,
    const float* __restrict__ a_w3, const float* __restrict__ a_b3,
    const float* __restrict__ mu_w, const float* __restrict__ mu_b,
    const float* __restrict__ sg_w, const float* __restrict__ sg_b,
    const float* __restrict__ aij_eps, const float* __restrict__ sij_eps,
    const int* __restrict__ cl, const float* __restrict__ utt,
    unsigned short* __restrict__ msgbf, unsigned short* __restrict__ h0bf,
    float* __restrict__ h0out) {
  int b = blockIdx.x, t = threadIdx.x;
  int w = t >> 6, l = t & 63;
  int a = cl[b] - 1;
  __shared__ float bn2r[4];
  {
    int p = (w >> 1) * 10 + a;
    int off = (w & 1) ? 10240 : 0;
    float s = 0.f;
#pragma unroll
    for (int k = 0; k < 8; ++k) s += Part2[off + p * 512 + l + k * 64];
    s = wred64(s);
    if (l == 0) bn2r[w] = s;
  }
  __syncthreads();
  __shared__ float sc2[4];  // sc2a, sh2a, sc2s, sh2s
  if (t < 2) {
    int br = t;
    const float invN = 1.f / (512.f * 10.f * 256.f);
    float m = bn2r[br * 2 + 0] * invN;
    float v = bn2r[br * 2 + 1] * invN - m * m;
    float g = br ? s_g2[a] : a_g2[a];
    float be = br ? s_be2[a] : a_be2[a];
    float sc = g / sqrtf(v + 1e-5f);
    sc2[br * 2] = sc;
    sc2[br * 2 + 1] = be - m * sc;
  }
  __syncthreads();
  float sc2a = sc2[0], sh2a = sc2[1], sc2s = sc2[2], sh2s = sc2[3];
  __shared__ float red[30];
#pragma unroll
  for (int m = 0; m < 3; ++m) {
    int j = w + 4 * m;
    if (j < 10) {
      float pa = 0.f, pm = 0.f, ps = 0.f;
#pragma unroll
      for (int cc = 0; cc < 4; ++cc) {
        int c = l + cc * 64;
        float za = bf2f(Z2a[(b * 10 + j) * 256 + c]);
        float va = fmaxf(za * sc2a + sh2a, 0.f);
        float zs = bf2f(Z2s[(b * 10 + j) * 256 + c]);
        float vs = tanh_fast(zs * sc2s + sh2s);
        pa += va * a_w3[c];
        pm += vs * mu_w[c];
        ps += vs * sg_w[c];
      }
      pa = wred64(pa); pm = wred64(pm); ps = wred64(ps);
      if (l == 0) { red[j] = pa; red[10 + j] = pm; red[20 + j] = ps; }
    }
  }
  __syncthreads();
  __shared__ float pw[10];
  __shared__ float wijs[16];
  if (t < 10) {
    int j = t;
    float amij = red[j] + a_b3[0];
    float amu = softplusf(amij) + 0.01f;
    float astd = sqrtf(softplusf((1.f - amu) * amu) + 0.01f);
    float ae = aij_eps[b * 100 + a * 10 + j];
    float aij = softplusf(ae * astd + amu) + 0.01f;
    float smu = red[10 + j] + mu_b[0];
    float ssg = red[20 + j] + sg_b[0];
    float se = sij_eps[b * 100 + a * 10 + j];
    float sij = se * sqrtf(aij * ssg * ssg) + aij * smu;
    wijs[j] = aij * sij;
  }
  __syncthreads();
  if (t == 0) {
    float mx = -1e30f;
    for (int j = 0; j < a; ++j) mx = fmaxf(mx, wijs[j]);
    float e[10];
    float den = 0.f;
    for (int j = 0; j < a; ++j) { e[j] = __expf(wijs[j] - mx); den += e[j]; }
    for (int j = 0; j < 10; ++j) pw[j] = (j < a) ? e[j] / den : 0.f;
  }
  __syncthreads();
#pragma unroll
  for (int dd = 0; dd < 2; ++dd) {
    int d = t + dd * 256;
    float mv = 0.f;
#pragma unroll
    for (int j = 0; j < 10; ++j) mv += pw[j] * utt[(b * 10 + j) * 512 + d];
    msgbf[b * 512 + d] = f2bf(mv);
  }
  float u1 = utt[(b * 10 + a) * 512 + t];
  float u2 = utt[(b * 10 + a) * 512 + 256 + t];
  float h0v = u1 + u2;
  h0out[b * 256 + t] = h0v;
  h0bf[b * 256 + t] = f2bf(h0v);
}

// ---------------- GRU elementwise (fast transcendentals) ----------------
__global__ __launch_bounds__(256) void gru_final(const float* __restrict__ gi,
                                                 const float* __restrict__ gh,
                                                 const float* __restrict__ h0,
                                                 float* __restrict__ out) {
  int idx = blockIdx.x * 256 + threadIdx.x;
  int b = idx >> 8, h = idx & 255;
  float ir = gi[b * 768 + h], iz = gi[b * 768 + 256 + h], inn = gi[b * 768 + 512 + h];
  float hr = gh[b * 768 + h], hz = gh[b * 768 + 256 + h], hn = gh[b * 768 + 512 + h];
  float r = sigmoid_fast(ir + hr);
  float z = sigmoid_fast(iz + hz);
  float n = tanh_fast(inn + r * hn);
  out[idx] = (1.f - z) * n + z * h0[b * 256 + h];
}

extern "C" void kernel_launch(void* const* d_in, const int* in_sizes, int n_in,
                              void* d_out, int out_size, void* d_ws, size_t ws_size,
                              hipStream_t stream) {
  const float* utt = (const float*)d_in[0];
  const float* aij_eps = (const float*)d_in[1];
  const float* sij_eps = (const float*)d_in[2];
  const int* cl = (const int*)d_in[3];
  const float* a_w1 = (const float*)d_in[4];
  const float* a_b1 = (const float*)d_in[5];
  const float* a_g1 = (const float*)d_in[6];
  const float* a_be1 = (const float*)d_in[7];
  const float* a_w2 = (const float*)d_in[8];
  const float* a_b2 = (const float*)d_in[9];
  const float* a_g2 = (const float*)d_in[10];
  const float* a_be2 = (const float*)d_in[11];
  const float* a_w3 = (const float*)d_in[12];
  const float* a_b3 = (const float*)d_in[13];
  const float* s_w1 = (const float*)d_in[14];
  const float* s_b1 = (const float*)d_in[15];
  const float* s_g1 = (const float*)d_in[16];
  const float* s_be1 = (const float*)d_in[17];
  const float* s_w2 = (const float*)d_in[18];
  const float* s_b2 = (const float*)d_in[19];
  const float* s_g2 = (const float*)d_in[20];
  const float* s_be2 = (const float*)d_in[21];
  const float* mu_w = (const float*)d_in[22];
  const float* mu_b = (const float*)d_in[23];
  const float* sg_w = (const float*)d_in[24];
  const float* sg_b = (const float*)d_in[25];
  const float* gru_wi = (const float*)d_in[26];
  const float* gru_wh = (const float*)d_in[27];
  const float* gru_bi = (const float*)d_in[28];
  const float* gru_bh = (const float*)d_in[29];

  float* ws = (float*)d_ws;
  float* ST = ws;                                            // 256 floats
  unsigned short* Af = (unsigned short*)(ws + 256);          // 2621440 sh
  unsigned short* Bf = Af + 2621440;                         // 524288 sh
  unsigned short* W2fa = Bf + 524288;                        // 65536 sh
  unsigned short* W2fs = W2fa + 65536;                       // 65536 sh
  unsigned short* wibf = W2fs + 65536;                       // 393216 sh
  unsigned short* whbf = wibf + 393216;                      // 196608 sh
  float* PQf = (float*)(whbf + 196608);                      // region: 5242880 f (PQ bf16 uses half)
  unsigned short* PQ = (unsigned short*)PQf;                 // 5242880 sh used
  unsigned short* Z2a = (unsigned short*)(PQf + 5242880);    // 1310720 sh
  unsigned short* Z2s = Z2a + 1310720;                       // 1310720 sh
  float* Part = PQf + 5242880 + 1310720;                     // 32768 f
  float* Part2 = Part + 32768;                               // 20480 f
  // postproc/GRU buffers alias the tail of the PQ region (PQ bf16 occupies first half only)
  float* tailf = PQf + 2621440;                              // 2621440 f free
  unsigned short* msgbf = (unsigned short*)tailf;            // 262144 sh
  unsigned short* h0bf = msgbf + 262144;                     // 131072 sh
  float* h0 = tailf + 196608;                                // 131072 f
  float* gi = tailf + 327680;                                // 393216 f
  float* gh = gi + 393216;                                   // 393216 f

  prep_weights<<<1888, 256, 0, stream>>>(utt, a_w1, s_w1, a_w2, s_w2, gru_wi, gru_wh,
                                         Af, Bf, W2fa, W2fs, wibf, whbf);
  gemm_pq_swz<<<dim3(80, 4), 256, 0, stream>>>(Af, Bf, PQ);
  stats_kernel<<<512, 256, 0, stream>>>(PQ, a_b1, s_b1, Part);
  reduce_bn1<<<2, 256, 0, stream>>>(Part, a_b1, s_b1, a_g1, a_be1, s_g1, s_be1, ST);
  fused_layer2_half<<<dim3(512, 2, 2), 256, 0, stream>>>(PQ, ST, a_b1, s_b1, W2fa, W2fs,
                                                         a_b2, s_b2, cl, Z2a, Z2s, Part2);
  postproc_kernel<<<512, 256, 0, stream>>>(Part2, a_g2, a_be2, s_g2, s_be2,
                                           Z2a, Z2s, a_w3, a_b3, mu_w, mu_b, sg_w, sg_b,
                                           aij_eps, sij_eps, cl, utt, msgbf, h0bf, h0);
  gemm_gru2<<<dim3(16, 3, 2), 256, 0, stream>>>(msgbf, wibf, gi, gru_bi,
                                                h0bf, whbf, gh, gru_bh);
  gru_final<<<512, 256, 0, stream>>>(gi, gh, h0, (float*)d_out);
}